// Round 9
// baseline (206.280 us; speedup 1.0000x reference)
//
#include <hip/hip_runtime.h>

// Problem constants: B=2, S=2048, D=1024, H=16, HD=64
#define SS 2048
#define SD 1024
#define SH 16
#define SHD 64
#define MROWS 4096
#define LOG2E 1.44269504088896340736f

typedef __attribute__((ext_vector_type(8))) short short8;
typedef __attribute__((ext_vector_type(4))) float floatx4;
typedef __attribute__((ext_vector_type(4))) unsigned short ushort4v;
typedef unsigned short u16;
typedef unsigned int u32;

#define AS1 __attribute__((address_space(1)))
#define AS3 __attribute__((address_space(3)))

__device__ inline u16 f2bf(float v) {
  u32 x = __builtin_bit_cast(u32, v);
  x = x + 0x7fffu + ((x >> 16) & 1u);   // RNE; inputs finite
  return (u16)(x >> 16);
}

// ---------------- fused cast kernel (all fp32 -> bf16 inputs) -------------
__global__ __launch_bounds__(256) void cast_all(
    const float* __restrict__ q, const float* __restrict__ k,
    const float* __restrict__ v, const float* __restrict__ wq,
    const float* __restrict__ wk, const float* __restrict__ wv,
    const float* __restrict__ wo, u16* __restrict__ out) {
  int i = blockIdx.x * 256 + threadIdx.x;
  const float* src;
  int idx;
  if (i < 3145728) {
    int a = i >> 20;
    src = (a == 0) ? q : ((a == 1) ? k : v);
    idx = i & 1048575;
  } else {
    int j = i - 3145728;
    int a = j >> 18;
    src = (a == 0) ? wq : ((a == 1) ? wk : ((a == 2) ? wv : wo));
    idx = j & 262143;
  }
  float4 f = ((const float4*)src)[idx];
  ushort4v o;
  o[0] = f2bf(f.x); o[1] = f2bf(f.y); o[2] = f2bf(f.z); o[3] = f2bf(f.w);
  ((ushort4v*)out)[i] = o;
}

// ---------------- GEMM: C[M,N] = A[M,K] @ W[N,K]^T + bias ----------------
// v9 (verified): BK=64, XOR-swizzled staging (involution verified),
// LDS-transpose epilogue -> fragment-major contiguous stores.
// Fragment layout F[bh][kt][ct][hh][lane][j]:
//   elem = X[bh, row=kt*64+ct*16+(lane&15), hd=hh*32+(lane>>4)*8+j]
//   linear = bh*131072 + (kt*8 + ct*2 + hh)*512 + lane*8 + j
// mode 0 only now; z=0 -> q frag-major (scaled), z=1 -> k frag-major,
//         z=2 -> V in PV-fragment-major layout (see attn).
__global__ __launch_bounds__(256, 3) void gemm_bt(
    const u16* __restrict__ Aall, const u16* __restrict__ Wall,
    const float* __restrict__ b0, const float* __restrict__ b1,
    const float* __restrict__ b2, u16* __restrict__ outb,
    float* __restrict__ outf, int mode, float qscale) {
  __shared__ u16 smem[16384];          // 32KB: staging, then epilogue LT
  u16* lds_a = smem;                   // [128][64]
  u16* lds_w = smem + 8192;            // [128][64]
  int z = blockIdx.z;
  const u16* A = Aall + (size_t)z * (MROWS * (size_t)SD);
  const u16* W = Wall + (size_t)z * (SD * (size_t)SD);
  const float* bias = (z == 0) ? b0 : ((z == 1) ? b1 : b2);
  float scale = (mode == 0 && z == 0) ? qscale : 1.0f;

  int tid = threadIdx.x;
  int lane = tid & 63, wave = tid >> 6;
  int l16 = lane & 15, quad = lane >> 4;
  int wm = (wave >> 1) * 64, wn = (wave & 1) * 64;
  int tm = blockIdx.y * 128, tn = blockIdx.x * 128;

  floatx4 acc[4][4];
  floatx4 zf = {0.f, 0.f, 0.f, 0.f};
#pragma unroll
  for (int r = 0; r < 4; r++)
#pragma unroll
    for (int c = 0; c < 4; c++) acc[r][c] = zf;

  // staging: 4 issue-rounds per matrix; round q covers rows q*32..q*32+32.
  // lane -> row = q*32 + wave*8 + (lane>>3), src col-chunk = (lane&7) XOR
  // (row&7)  => LDS(row, slot s) holds global chunk s ^ (row&7).
  const u16* pa[4];
  const u16* pw[4];
#pragma unroll
  for (int q = 0; q < 4; q++) {
    int srow = q * 32 + wave * 8 + (lane >> 3);
    int scol = (((lane & 7) ^ ((lane >> 3) & 7)) << 3);
    pa[q] = A + (size_t)(tm + srow) * SD + scol;
    pw[q] = W + (size_t)(tn + srow) * SD + scol;
  }

  for (int k0 = 0; k0 < SD; k0 += 64) {
#pragma unroll
    for (int q = 0; q < 4; q++) {
      __builtin_amdgcn_global_load_lds((const AS1 void*)pa[q],
          (AS3 void*)(AS3 u16*)&lds_a[(q * 32 + wave * 8) * 64], 16, 0, 0);
      __builtin_amdgcn_global_load_lds((const AS1 void*)pw[q],
          (AS3 void*)(AS3 u16*)&lds_w[(q * 32 + wave * 8) * 64], 16, 0, 0);
      pa[q] += 64; pw[q] += 64;
    }
    __syncthreads();
    short8 af[4][2], wf[4][2];
#pragma unroll
    for (int r = 0; r < 4; r++)
#pragma unroll
      for (int kk = 0; kk < 2; kk++)
        af[r][kk] = *(short8*)&lds_a[(wm + r * 16 + l16) * 64 +
                                     (((kk * 4 + quad) ^ (l16 & 7)) << 3)];
#pragma unroll
    for (int c = 0; c < 4; c++)
#pragma unroll
      for (int kk = 0; kk < 2; kk++)
        wf[c][kk] = *(short8*)&lds_w[(wn + c * 16 + l16) * 64 +
                                     (((kk * 4 + quad) ^ (l16 & 7)) << 3)];
#pragma unroll
    for (int r = 0; r < 4; r++)
#pragma unroll
      for (int c = 0; c < 4; c++) {
        acc[r][c] = __builtin_amdgcn_mfma_f32_16x16x32_bf16(af[r][0], wf[c][0], acc[r][c], 0, 0, 0);
        acc[r][c] = __builtin_amdgcn_mfma_f32_16x16x32_bf16(af[r][1], wf[c][1], acc[r][c], 0, 0, 0);
      }
    __syncthreads();
  }

  if (mode == 0) {
    u16* ob = outb + (size_t)z * (MROWS * (size_t)SD);
    if (z < 2) {
      // ---- LDS-transpose epilogue -> fragment-major contiguous stores ----
      // LT[key][128]: value for (key,feat) stored at 16B-chunk
      // (feat>>3)^(key&7), byte-offset feat&7.
      u16* LT = smem;
#pragma unroll
      for (int r = 0; r < 4; r++) {
#pragma unroll
        for (int c = 0; c < 4; c++) {
          int feat = wn + c * 16 + l16;
          float bv = bias[tn + feat];
#pragma unroll
          for (int g = 0; g < 4; g++) {
            int key = wm + r * 16 + quad * 4 + g;
            float val = (acc[r][c][g] + bv) * scale;
            LT[key * 128 + ((((feat >> 3) ^ (key & 7)) << 3) | (feat & 7))] = f2bf(val);
          }
        }
      }
      __syncthreads();
      int bb = tm >> 11;
      int kt0 = (tm & 2047) >> 6;
#pragma unroll
      for (int i = 0; i < 8; i++) {
        int id = wave * 8 + i;  // 32 chunks of 512 u16
        int kt_rel = id >> 4, hrel = (id >> 3) & 1, ct = (id >> 1) & 3, hh = id & 1;
        int key = kt_rel * 64 + ct * 16 + l16;
        int chunk = hrel * 8 + hh * 4 + quad;
        short8 vv = *(short8*)&LT[key * 128 + ((chunk ^ (l16 & 7)) << 3)];
        int h = (tn >> 6) + hrel;
        u16* dst = ob + (size_t)(bb * SH + h) * (SS * SHD) +
                   ((kt0 + kt_rel) * 8 + ct * 2 + hh) * 512 + lane * 8;
        *(short8*)dst = vv;
      }
    } else {
      // z==2: V in PV-fragment-major layout. Per head, per 64-key tile kt:
      // 8 blocks (c*2+ct2) of 512 elems; lane slot (l16*4+quad)*8; elems
      // [half*4+j] = V[key=kt*64+ct*16+quad*4+j, hd=c*16+l16], ct=2*ct2+half.
      int h = (tn + wn) >> 6;
      int bb = (tm + wm) >> 11;
      int kt = ((tm + wm) & 2047) >> 6;
      u16* vbase = ob + (size_t)(bb * SH + h) * (SS * SHD) + (size_t)kt * 4096 +
                   (l16 * 4 + quad) * 8;
#pragma unroll
      for (int c = 0; c < 4; c++) {
        int gn = tn + wn + c * 16 + l16;
        float bv = bias[gn];
#pragma unroll
        for (int rp = 0; rp < 2; rp++) {
          union { u16 u[8]; short8 s; } pk;
#pragma unroll
          for (int g = 0; g < 4; g++) {
            pk.u[g]     = f2bf(acc[2 * rp][c][g] + bv);
            pk.u[4 + g] = f2bf(acc[2 * rp + 1][c][g] + bv);
          }
          *(short8*)&vbase[(c * 2 + rp) * 512] = pk.s;
        }
      }
    }
  } else {
#pragma unroll
    for (int r = 0; r < 4; r++) {
#pragma unroll
      for (int c = 0; c < 4; c++) {
        int gn = tn + wn + c * 16 + l16;
        float bv = bias[gn];
#pragma unroll
        for (int g = 0; g < 4; g++) {
          int gm = tm + wm + r * 16 + quad * 4 + g;
          outf[(size_t)gm * SD + gn] = acc[r][c][g] + bv;
        }
      }
    }
  }
}

// ---------------- O-projection GEMM: out[M,N] = A @ Wo^T + bo (fp32) -----
// 64x128 tiles, grid (8,64) = 512 blocks = 2 blocks/CU = 2 waves/SIMD.
// Verified round 8 (209.5 -> 203.5 us total).
__global__ __launch_bounds__(256, 2) void gemm_o(
    const u16* __restrict__ A, const u16* __restrict__ W,
    const float* __restrict__ bias, float* __restrict__ outf) {
  __shared__ u16 lds_a[64 * 64];    // 8 KB
  __shared__ u16 lds_w[128 * 64];   // 16 KB
  int tid = threadIdx.x;
  int lane = tid & 63, wave = tid >> 6;
  int l16 = lane & 15, quad = lane >> 4;
  int wm = (wave >> 1) * 32, wn = (wave & 1) * 64;
  int tm = blockIdx.y * 64, tn = blockIdx.x * 128;

  floatx4 acc[2][4];
  floatx4 zf = {0.f, 0.f, 0.f, 0.f};
#pragma unroll
  for (int r = 0; r < 2; r++)
#pragma unroll
    for (int c = 0; c < 4; c++) acc[r][c] = zf;

  int srow8 = wave * 8 + (lane >> 3);
  int scol = (((lane & 7) ^ ((lane >> 3) & 7)) << 3);
  const u16* pa[2];
  const u16* pw[4];
#pragma unroll
  for (int q = 0; q < 2; q++)
    pa[q] = A + (size_t)(tm + q * 32 + srow8) * SD + scol;
#pragma unroll
  for (int q = 0; q < 4; q++)
    pw[q] = W + (size_t)(tn + q * 32 + srow8) * SD + scol;

  for (int k0 = 0; k0 < SD; k0 += 64) {
#pragma unroll
    for (int q = 0; q < 2; q++) {
      __builtin_amdgcn_global_load_lds((const AS1 void*)pa[q],
          (AS3 void*)(AS3 u16*)&lds_a[(q * 32 + wave * 8) * 64], 16, 0, 0);
      pa[q] += 64;
    }
#pragma unroll
    for (int q = 0; q < 4; q++) {
      __builtin_amdgcn_global_load_lds((const AS1 void*)pw[q],
          (AS3 void*)(AS3 u16*)&lds_w[(q * 32 + wave * 8) * 64], 16, 0, 0);
      pw[q] += 64;
    }
    __syncthreads();
    short8 af[2][2], wf[4][2];
#pragma unroll
    for (int r = 0; r < 2; r++)
#pragma unroll
      for (int kk = 0; kk < 2; kk++)
        af[r][kk] = *(short8*)&lds_a[(wm + r * 16 + l16) * 64 +
                                     (((kk * 4 + quad) ^ (l16 & 7)) << 3)];
#pragma unroll
    for (int c = 0; c < 4; c++)
#pragma unroll
      for (int kk = 0; kk < 2; kk++)
        wf[c][kk] = *(short8*)&lds_w[(wn + c * 16 + l16) * 64 +
                                     (((kk * 4 + quad) ^ (l16 & 7)) << 3)];
#pragma unroll
    for (int r = 0; r < 2; r++)
#pragma unroll
      for (int c = 0; c < 4; c++) {
        acc[r][c] = __builtin_amdgcn_mfma_f32_16x16x32_bf16(af[r][0], wf[c][0], acc[r][c], 0, 0, 0);
        acc[r][c] = __builtin_amdgcn_mfma_f32_16x16x32_bf16(af[r][1], wf[c][1], acc[r][c], 0, 0, 0);
      }
    __syncthreads();
  }

#pragma unroll
  for (int r = 0; r < 2; r++) {
#pragma unroll
    for (int c = 0; c < 4; c++) {
      int gn = tn + wn + c * 16 + l16;
      float bv = bias[gn];
#pragma unroll
      for (int g = 0; g < 4; g++) {
        int gm = tm + wm + r * 16 + quad * 4 + g;
        outf[(size_t)gm * SD + gn] = acc[r][c][g] + bv;
      }
    }
  }
}

// ---------------- flash attention v11: cross-phase softmax pipeline ------
// v9 stall analysis: each phase issued 16 QK MFMAs then immediately exp2'd
// their results -> ~40-cyc MFMA-latency bubble per phase, only partially
// covered by the one co-resident wave (MfmaUtil 39%).  v11 pipelines one
// phase deep, crossing the boundary with the PACKED P (paA/paB, 16 VGPR
// per set) instead of raw scores: phase order = QK(p) issue -> kf prefetch
// -> PV(p-1) (20 independent MFMA issues cover QK(p) latency) -> vf
// prefetch -> exp2+pack(p).  The QK->exp2 stall vanishes; MFMA issues run
// back-to-back.  Accumulation order over pairs unchanged -> bit-identical.
// Registers: ~150 arch + 80 acc ~= 230 <= 256 (2 waves/SIMD budget).
// Phase parity hand-unrolled (paA/paB static names); prologue peels the
// first two phases; epilogue drains the last PV.
__global__ __launch_bounds__(128, 2) void attn(
    const u16* __restrict__ qb, const u16* __restrict__ kb,
    const u16* __restrict__ vfrag, u16* __restrict__ ctxb) {
  int lane = threadIdx.x & 63;
  int wave = threadIdx.x >> 6;          // 0 or 1: kv-half owner
  int l16 = lane & 15, quad = lane >> 4;

  // XCD swizzle: 4 heads per XCD residue (2 MB K+V working set per L2)
  int raw = blockIdx.x;                // 0..1023
  int xcd = raw & 7, slot = raw >> 3;  // slot 0..127
  int bh = xcd + 8 * (slot >> 5);
  int qt = slot & 31;
  int b = bh >> 4, h = bh & 15;
  int base = bh * (SS * SHD);
  int q0 = qt * 64;

  const u16* kp = kb + base + lane * 8;                 // + (kt*8+ct*2+hh)*512
  const u16* vp = vfrag + base + (l16 * 4 + quad) * 8;  // + kt*4096 + (c*2+c2)*512

  // Q fragments (B operand of S^T), fragment-major: kt=qt, ct=t
  short8 qf[4][2];
#pragma unroll
  for (int t = 0; t < 4; t++)
#pragma unroll
    for (int hh = 0; hh < 2; hh++)
      qf[t][hh] = *(const short8*)&qb[base + (qt * 8 + t * 2 + hh) * 512 + lane * 8];

  floatx4 zf = {0.f, 0.f, 0.f, 0.f};
  floatx4 acc[4][4], accl[4];
#pragma unroll
  for (int t = 0; t < 4; t++) {
    accl[t] = zf;
#pragma unroll
    for (int c = 0; c < 4; c++) acc[t][c] = zf;
  }
  const short8 ones8 = {0x3F80, 0x3F80, 0x3F80, 0x3F80,
                        0x3F80, 0x3F80, 0x3F80, 0x3F80};  // bf16 1.0 x8

  // wave w owns kv-tiles [w*16, w*16+16)
  int ktbase = wave * 16;
  short8 kf[4][2], vf[4][2];
  floatx4 se[4], so[4];
  short8 paA[4], paB[4];

#define QK_PAIR(CT0, CT1)                                                     \
  do {                                                                        \
    _Pragma("unroll")                                                         \
    for (int t = 0; t < 4; t++) {                                             \
      floatx4 zz = zf;                                                        \
      zz = __builtin_amdgcn_mfma_f32_16x16x32_bf16(kf[CT0][0], qf[t][0], zz, 0, 0, 0); \
      zz = __builtin_amdgcn_mfma_f32_16x16x32_bf16(kf[CT0][1], qf[t][1], zz, 0, 0, 0); \
      se[t] = zz;                                                             \
      floatx4 ww = zf;                                                        \
      ww = __builtin_amdgcn_mfma_f32_16x16x32_bf16(kf[CT1][0], qf[t][0], ww, 0, 0, 0); \
      ww = __builtin_amdgcn_mfma_f32_16x16x32_bf16(kf[CT1][1], qf[t][1], ww, 0, 0, 0); \
      so[t] = ww;                                                             \
    }                                                                         \
  } while (0)

#define PACK(PA)                                                              \
  do {                                                                        \
    _Pragma("unroll")                                                         \
    for (int t = 0; t < 4; t++) {                                             \
      u32 e0 = __builtin_bit_cast(u32, __builtin_amdgcn_exp2f(se[t][0]));     \
      u32 e1 = __builtin_bit_cast(u32, __builtin_amdgcn_exp2f(se[t][1]));     \
      u32 e2 = __builtin_bit_cast(u32, __builtin_amdgcn_exp2f(se[t][2]));     \
      u32 e3 = __builtin_bit_cast(u32, __builtin_amdgcn_exp2f(se[t][3]));     \
      u32 o0 = __builtin_bit_cast(u32, __builtin_amdgcn_exp2f(so[t][0]));     \
      u32 o1 = __builtin_bit_cast(u32, __builtin_amdgcn_exp2f(so[t][1]));     \
      u32 o2 = __builtin_bit_cast(u32, __builtin_amdgcn_exp2f(so[t][2]));     \
      u32 o3 = __builtin_bit_cast(u32, __builtin_amdgcn_exp2f(so[t][3]));     \
      union { u32 u[4]; short8 s; } pk;                                       \
      pk.u[0] = __builtin_amdgcn_perm(e1, e0, 0x07060302);                    \
      pk.u[1] = __builtin_amdgcn_perm(e3, e2, 0x07060302);                    \
      pk.u[2] = __builtin_amdgcn_perm(o1, o0, 0x07060302);                    \
      pk.u[3] = __builtin_amdgcn_perm(o3, o2, 0x07060302);                    \
      PA[t] = pk.s;                                                           \
    }                                                                         \
  } while (0)

#define PVACC(PA, C2)                                                         \
  do {                                                                        \
    _Pragma("unroll")                                                         \
    for (int t = 0; t < 4; t++) {                                             \
      _Pragma("unroll")                                                       \
      for (int c = 0; c < 4; c++)                                             \
        acc[t][c] = __builtin_amdgcn_mfma_f32_16x16x32_bf16(PA[t], vf[c][C2], acc[t][c], 0, 0, 0); \
      accl[t] = __builtin_amdgcn_mfma_f32_16x16x32_bf16(PA[t], ones8, accl[t], 0, 0, 0); \
    }                                                                         \
  } while (0)

#define LDK(PAIR, PTR)                                                        \
  do {                                                                        \
    kf[2*(PAIR)][0]   = *(const short8*)&(PTR)[(2*(PAIR)*2 + 0) * 512];       \
    kf[2*(PAIR)][1]   = *(const short8*)&(PTR)[(2*(PAIR)*2 + 1) * 512];       \
    kf[2*(PAIR)+1][0] = *(const short8*)&(PTR)[((2*(PAIR)+1)*2 + 0) * 512];   \
    kf[2*(PAIR)+1][1] = *(const short8*)&(PTR)[((2*(PAIR)+1)*2 + 1) * 512];   \
  } while (0)

#define LDV(C2, PTR)                                                          \
  do {                                                                        \
    _Pragma("unroll")                                                         \
    for (int c = 0; c < 4; c++)                                               \
      vf[c][C2] = *(const short8*)&(PTR)[(c * 2 + (C2)) * 512];               \
  } while (0)

  // prologue loads: kf all 4 cts, vf half 0, tile ktbase
  LDK(0, kp + ktbase * 4096);
  LDK(1, kp + ktbase * 4096);
  LDV(0, vp + ktbase * 4096);

  // peel phase (t0,0): QK only, no PV yet
  {
    const u16* kpn = kp + (ktbase + 1) * 4096;
    QK_PAIR(0, 1);
    LDK(0, kpn);                        // kf pair0 <- tile+1
    LDV(1, vp + ktbase * 4096);         // vf half1 <- tile 0
    PACK(paA);
  }
  // peel phase (t0,1): PV of phase (t0,0)
  {
    const u16* kpn = kp + (ktbase + 1) * 4096;
    const u16* vpn = vp + (ktbase + 1) * 4096;
    QK_PAIR(2, 3);
    LDK(1, kpn);                        // kf pair1 <- tile+1
    PVACC(paA, 0);                      // PV(tile0, pair0)
    LDV(0, vpn);                        // vf half0 <- tile 1
    PACK(paB);
  }

#pragma unroll 1
  for (int r = 1; r < 16; r++) {
    int nt = ktbase + ((r + 1) & 15);   // wrap-safe dummy prefetch on last
    const u16* kpn = kp + nt * 4096;
    const u16* vpn = vp + nt * 4096;
    const u16* vpc = vp + (ktbase + r) * 4096;
    // phase (r,0):
    QK_PAIR(0, 1);                      // kf pair0 = tile r
    LDK(0, kpn);                        // <- tile r+1
    PVACC(paB, 1);                      // PV(r-1,1); vf half1 = tile r-1
    LDV(1, vpc);                        // vf half1 <- tile r
    PACK(paA);
    // phase (r,1):
    QK_PAIR(2, 3);                      // kf pair1 = tile r
    LDK(1, kpn);
    PVACC(paA, 0);                      // PV(r,0); vf half0 = tile r
    LDV(0, vpn);                        // vf half0 <- tile r+1
    PACK(paB);
  }
  // epilogue: drain last PV (tile t0+15, pair 1)
  PVACC(paB, 1);

#undef QK_PAIR
#undef PACK
#undef PVACC
#undef LDK
#undef LDV

  // Cross-wave combine: wave w publishes the OTHER wave's t-half, then each
  // wave sums partials for its own t-half and stores those 32 q-rows.
  __shared__ floatx4 red[2][64][11];  // [dest wave][lane][(t&1)*5 + c; 4=accl]
  int ow = 1 - wave;
#pragma unroll
  for (int t = 0; t < 4; t++) {
    if ((t >> 1) == ow) {
#pragma unroll
      for (int c = 0; c < 4; c++) red[ow][lane][(t & 1) * 5 + c] = acc[t][c];
      red[ow][lane][(t & 1) * 5 + 4] = accl[t];
    }
  }
  __syncthreads();
#pragma unroll
  for (int t = 0; t < 4; t++) {
    if ((t >> 1) == wave) {
#pragma unroll
      for (int c = 0; c < 4; c++) acc[t][c] += red[wave][lane][(t & 1) * 5 + c];
      accl[t] += red[wave][lane][(t & 1) * 5 + 4];
    }
  }

  // epilogue: l per-row in accl (no shuffles); each wave stores its t-half
#pragma unroll
  for (int t = 0; t < 4; t++) {
    if ((t >> 1) == wave) {
#pragma unroll
      for (int g = 0; g < 4; g++) {
        float invg = 1.0f / accl[t][g];
        int qrow = q0 + t * 16 + quad * 4 + g;
#pragma unroll
        for (int c = 0; c < 4; c++) {
          int hd = c * 16 + l16;
          ctxb[(size_t)((b * SS + qrow) * SD + h * SHD + hd)] = f2bf(acc[t][c][g] * invg);
        }
      }
    }
  }
}

// ---------------- launch ----------------
extern "C" void kernel_launch(void* const* d_in, const int* in_sizes, int n_in,
                              void* d_out, int out_size, void* d_ws, size_t ws_size,
                              hipStream_t stream) {
  const float* Q  = (const float*)d_in[0];
  const float* Kp = (const float*)d_in[1];
  const float* Vp = (const float*)d_in[2];
  const float* Wq = (const float*)d_in[3];
  const float* bq = (const float*)d_in[4];
  const float* Wk = (const float*)d_in[5];
  const float* bk = (const float*)d_in[6];
  const float* Wv = (const float*)d_in[7];
  const float* bv = (const float*)d_in[8];
  const float* Wo = (const float*)d_in[9];
  const float* bo = (const float*)d_in[10];

  u16* xb   = (u16*)d_ws;                        // 3 * 4,194,304  bf16 Q,K,V
  u16* wb   = xb + (size_t)3 * 4194304;          // 4 * 1,048,576  bf16 weights
  u16* qkvb = wb + (size_t)4 * 1048576;          // q,k frag-major; V frag-major
  u16* ctxb = qkvb + (size_t)3 * 4194304;        // ctx [B,S,D]
  float* out = (float*)d_out;

  cast_all<<<dim3(16384), dim3(256), 0, stream>>>(Q, Kp, Vp, Wq, Wk, Wv, Wo, xb);

  const float qscale = 0.125f * LOG2E;
  gemm_bt<<<dim3(8, 32, 3), dim3(256), 0, stream>>>(
      xb, wb, bq, bk, bv, qkvb, (float*)nullptr, 0, qscale);

  attn<<<dim3(1024), dim3(128), 0, stream>>>(
      qkvb, qkvb + (size_t)4194304, qkvb + (size_t)2 * 4194304, ctxb);

  gemm_o<<<dim3(8, 64), dim3(256), 0, stream>>>(
      ctxb, wb + (size_t)3 * 1048576, bo, out);
}

// Round 10
// 202.102 us; speedup vs baseline: 1.0207x; 1.0207x over previous
//
#include <hip/hip_runtime.h>

// Problem constants: B=2, S=2048, D=1024, H=16, HD=64
#define SS 2048
#define SD 1024
#define SH 16
#define SHD 64
#define MROWS 4096
#define LOG2E 1.44269504088896340736f

typedef __attribute__((ext_vector_type(8))) short short8;
typedef __attribute__((ext_vector_type(4))) float floatx4;
typedef __attribute__((ext_vector_type(4))) unsigned short ushort4v;
typedef unsigned short u16;
typedef unsigned int u32;

#define AS1 __attribute__((address_space(1)))
#define AS3 __attribute__((address_space(3)))

__device__ inline u16 f2bf(float v) {
  u32 x = __builtin_bit_cast(u32, v);
  x = x + 0x7fffu + ((x >> 16) & 1u);   // RNE; inputs finite
  return (u16)(x >> 16);
}

// ---------------- fused cast kernel (all fp32 -> bf16 inputs) -------------
__global__ __launch_bounds__(256) void cast_all(
    const float* __restrict__ q, const float* __restrict__ k,
    const float* __restrict__ v, const float* __restrict__ wq,
    const float* __restrict__ wk, const float* __restrict__ wv,
    const float* __restrict__ wo, u16* __restrict__ out) {
  int i = blockIdx.x * 256 + threadIdx.x;
  const float* src;
  int idx;
  if (i < 3145728) {
    int a = i >> 20;
    src = (a == 0) ? q : ((a == 1) ? k : v);
    idx = i & 1048575;
  } else {
    int j = i - 3145728;
    int a = j >> 18;
    src = (a == 0) ? wq : ((a == 1) ? wk : ((a == 2) ? wv : wo));
    idx = j & 262143;
  }
  float4 f = ((const float4*)src)[idx];
  ushort4v o;
  o[0] = f2bf(f.x); o[1] = f2bf(f.y); o[2] = f2bf(f.z); o[3] = f2bf(f.w);
  ((ushort4v*)out)[i] = o;
}

// ---------------- GEMM: C[M,N] = A[M,K] @ W[N,K]^T + bias ----------------
// v9 (verified): BK=64, XOR-swizzled staging (involution verified),
// LDS-transpose epilogue -> fragment-major contiguous stores.
// Fragment layout F[bh][kt][ct][hh][lane][j]:
//   elem = X[bh, row=kt*64+ct*16+(lane&15), hd=hh*32+(lane>>4)*8+j]
//   linear = bh*131072 + (kt*8 + ct*2 + hh)*512 + lane*8 + j
// mode 0 only now; z=0 -> q frag-major (scaled), z=1 -> k frag-major,
//         z=2 -> V in PV-fragment-major layout (see attn).
__global__ __launch_bounds__(256, 3) void gemm_bt(
    const u16* __restrict__ Aall, const u16* __restrict__ Wall,
    const float* __restrict__ b0, const float* __restrict__ b1,
    const float* __restrict__ b2, u16* __restrict__ outb,
    float* __restrict__ outf, int mode, float qscale) {
  __shared__ u16 smem[16384];          // 32KB: staging, then epilogue LT
  u16* lds_a = smem;                   // [128][64]
  u16* lds_w = smem + 8192;            // [128][64]
  int z = blockIdx.z;
  const u16* A = Aall + (size_t)z * (MROWS * (size_t)SD);
  const u16* W = Wall + (size_t)z * (SD * (size_t)SD);
  const float* bias = (z == 0) ? b0 : ((z == 1) ? b1 : b2);
  float scale = (mode == 0 && z == 0) ? qscale : 1.0f;

  int tid = threadIdx.x;
  int lane = tid & 63, wave = tid >> 6;
  int l16 = lane & 15, quad = lane >> 4;
  int wm = (wave >> 1) * 64, wn = (wave & 1) * 64;
  int tm = blockIdx.y * 128, tn = blockIdx.x * 128;

  floatx4 acc[4][4];
  floatx4 zf = {0.f, 0.f, 0.f, 0.f};
#pragma unroll
  for (int r = 0; r < 4; r++)
#pragma unroll
    for (int c = 0; c < 4; c++) acc[r][c] = zf;

  // staging: 4 issue-rounds per matrix; round q covers rows q*32..q*32+32.
  // lane -> row = q*32 + wave*8 + (lane>>3), src col-chunk = (lane&7) XOR
  // (row&7)  => LDS(row, slot s) holds global chunk s ^ (row&7).
  const u16* pa[4];
  const u16* pw[4];
#pragma unroll
  for (int q = 0; q < 4; q++) {
    int srow = q * 32 + wave * 8 + (lane >> 3);
    int scol = (((lane & 7) ^ ((lane >> 3) & 7)) << 3);
    pa[q] = A + (size_t)(tm + srow) * SD + scol;
    pw[q] = W + (size_t)(tn + srow) * SD + scol;
  }

  for (int k0 = 0; k0 < SD; k0 += 64) {
#pragma unroll
    for (int q = 0; q < 4; q++) {
      __builtin_amdgcn_global_load_lds((const AS1 void*)pa[q],
          (AS3 void*)(AS3 u16*)&lds_a[(q * 32 + wave * 8) * 64], 16, 0, 0);
      __builtin_amdgcn_global_load_lds((const AS1 void*)pw[q],
          (AS3 void*)(AS3 u16*)&lds_w[(q * 32 + wave * 8) * 64], 16, 0, 0);
      pa[q] += 64; pw[q] += 64;
    }
    __syncthreads();
    short8 af[4][2], wf[4][2];
#pragma unroll
    for (int r = 0; r < 4; r++)
#pragma unroll
      for (int kk = 0; kk < 2; kk++)
        af[r][kk] = *(short8*)&lds_a[(wm + r * 16 + l16) * 64 +
                                     (((kk * 4 + quad) ^ (l16 & 7)) << 3)];
#pragma unroll
    for (int c = 0; c < 4; c++)
#pragma unroll
      for (int kk = 0; kk < 2; kk++)
        wf[c][kk] = *(short8*)&lds_w[(wn + c * 16 + l16) * 64 +
                                     (((kk * 4 + quad) ^ (l16 & 7)) << 3)];
#pragma unroll
    for (int r = 0; r < 4; r++)
#pragma unroll
      for (int c = 0; c < 4; c++) {
        acc[r][c] = __builtin_amdgcn_mfma_f32_16x16x32_bf16(af[r][0], wf[c][0], acc[r][c], 0, 0, 0);
        acc[r][c] = __builtin_amdgcn_mfma_f32_16x16x32_bf16(af[r][1], wf[c][1], acc[r][c], 0, 0, 0);
      }
    __syncthreads();
  }

  if (mode == 0) {
    u16* ob = outb + (size_t)z * (MROWS * (size_t)SD);
    if (z < 2) {
      // ---- LDS-transpose epilogue -> fragment-major contiguous stores ----
      // LT[key][128]: value for (key,feat) stored at 16B-chunk
      // (feat>>3)^(key&7), byte-offset feat&7.
      u16* LT = smem;
#pragma unroll
      for (int r = 0; r < 4; r++) {
#pragma unroll
        for (int c = 0; c < 4; c++) {
          int feat = wn + c * 16 + l16;
          float bv = bias[tn + feat];
#pragma unroll
          for (int g = 0; g < 4; g++) {
            int key = wm + r * 16 + quad * 4 + g;
            float val = (acc[r][c][g] + bv) * scale;
            LT[key * 128 + ((((feat >> 3) ^ (key & 7)) << 3) | (feat & 7))] = f2bf(val);
          }
        }
      }
      __syncthreads();
      int bb = tm >> 11;
      int kt0 = (tm & 2047) >> 6;
#pragma unroll
      for (int i = 0; i < 8; i++) {
        int id = wave * 8 + i;  // 32 chunks of 512 u16
        int kt_rel = id >> 4, hrel = (id >> 3) & 1, ct = (id >> 1) & 3, hh = id & 1;
        int key = kt_rel * 64 + ct * 16 + l16;
        int chunk = hrel * 8 + hh * 4 + quad;
        short8 vv = *(short8*)&LT[key * 128 + ((chunk ^ (l16 & 7)) << 3)];
        int h = (tn >> 6) + hrel;
        u16* dst = ob + (size_t)(bb * SH + h) * (SS * SHD) +
                   ((kt0 + kt_rel) * 8 + ct * 2 + hh) * 512 + lane * 8;
        *(short8*)dst = vv;
      }
    } else {
      // z==2: V in PV-fragment-major layout. Per head, per 64-key tile kt:
      // 8 blocks (c*2+ct2) of 512 elems; lane slot (l16*4+quad)*8; elems
      // [half*4+j] = V[key=kt*64+ct*16+quad*4+j, hd=c*16+l16], ct=2*ct2+half.
      int h = (tn + wn) >> 6;
      int bb = (tm + wm) >> 11;
      int kt = ((tm + wm) & 2047) >> 6;
      u16* vbase = ob + (size_t)(bb * SH + h) * (SS * SHD) + (size_t)kt * 4096 +
                   (l16 * 4 + quad) * 8;
#pragma unroll
      for (int c = 0; c < 4; c++) {
        int gn = tn + wn + c * 16 + l16;
        float bv = bias[gn];
#pragma unroll
        for (int rp = 0; rp < 2; rp++) {
          union { u16 u[8]; short8 s; } pk;
#pragma unroll
          for (int g = 0; g < 4; g++) {
            pk.u[g]     = f2bf(acc[2 * rp][c][g] + bv);
            pk.u[4 + g] = f2bf(acc[2 * rp + 1][c][g] + bv);
          }
          *(short8*)&vbase[(c * 2 + rp) * 512] = pk.s;
        }
      }
    }
  } else {
#pragma unroll
    for (int r = 0; r < 4; r++) {
#pragma unroll
      for (int c = 0; c < 4; c++) {
        int gn = tn + wn + c * 16 + l16;
        float bv = bias[gn];
#pragma unroll
        for (int g = 0; g < 4; g++) {
          int gm = tm + wm + r * 16 + quad * 4 + g;
          outf[(size_t)gm * SD + gn] = acc[r][c][g] + bv;
        }
      }
    }
  }
}

// ---------------- O-projection GEMM: out[M,N] = A @ Wo^T + bo (fp32) -----
// 64x128 tiles, grid (8,64) = 512 blocks = 2 blocks/CU = 2 waves/SIMD.
// Verified round 8 (209.5 -> 203.5 us total).
__global__ __launch_bounds__(256, 2) void gemm_o(
    const u16* __restrict__ A, const u16* __restrict__ W,
    const float* __restrict__ bias, float* __restrict__ outf) {
  __shared__ u16 lds_a[64 * 64];    // 8 KB
  __shared__ u16 lds_w[128 * 64];   // 16 KB
  int tid = threadIdx.x;
  int lane = tid & 63, wave = tid >> 6;
  int l16 = lane & 15, quad = lane >> 4;
  int wm = (wave >> 1) * 32, wn = (wave & 1) * 64;
  int tm = blockIdx.y * 64, tn = blockIdx.x * 128;

  floatx4 acc[2][4];
  floatx4 zf = {0.f, 0.f, 0.f, 0.f};
#pragma unroll
  for (int r = 0; r < 2; r++)
#pragma unroll
    for (int c = 0; c < 4; c++) acc[r][c] = zf;

  int srow8 = wave * 8 + (lane >> 3);
  int scol = (((lane & 7) ^ ((lane >> 3) & 7)) << 3);
  const u16* pa[2];
  const u16* pw[4];
#pragma unroll
  for (int q = 0; q < 2; q++)
    pa[q] = A + (size_t)(tm + q * 32 + srow8) * SD + scol;
#pragma unroll
  for (int q = 0; q < 4; q++)
    pw[q] = W + (size_t)(tn + q * 32 + srow8) * SD + scol;

  for (int k0 = 0; k0 < SD; k0 += 64) {
#pragma unroll
    for (int q = 0; q < 2; q++) {
      __builtin_amdgcn_global_load_lds((const AS1 void*)pa[q],
          (AS3 void*)(AS3 u16*)&lds_a[(q * 32 + wave * 8) * 64], 16, 0, 0);
      pa[q] += 64;
    }
#pragma unroll
    for (int q = 0; q < 4; q++) {
      __builtin_amdgcn_global_load_lds((const AS1 void*)pw[q],
          (AS3 void*)(AS3 u16*)&lds_w[(q * 32 + wave * 8) * 64], 16, 0, 0);
      pw[q] += 64;
    }
    __syncthreads();
    short8 af[2][2], wf[4][2];
#pragma unroll
    for (int r = 0; r < 2; r++)
#pragma unroll
      for (int kk = 0; kk < 2; kk++)
        af[r][kk] = *(short8*)&lds_a[(wm + r * 16 + l16) * 64 +
                                     (((kk * 4 + quad) ^ (l16 & 7)) << 3)];
#pragma unroll
    for (int c = 0; c < 4; c++)
#pragma unroll
      for (int kk = 0; kk < 2; kk++)
        wf[c][kk] = *(short8*)&lds_w[(wn + c * 16 + l16) * 64 +
                                     (((kk * 4 + quad) ^ (l16 & 7)) << 3)];
#pragma unroll
    for (int r = 0; r < 2; r++)
#pragma unroll
      for (int c = 0; c < 4; c++) {
        acc[r][c] = __builtin_amdgcn_mfma_f32_16x16x32_bf16(af[r][0], wf[c][0], acc[r][c], 0, 0, 0);
        acc[r][c] = __builtin_amdgcn_mfma_f32_16x16x32_bf16(af[r][1], wf[c][1], acc[r][c], 0, 0, 0);
      }
    __syncthreads();
  }

#pragma unroll
  for (int r = 0; r < 2; r++) {
#pragma unroll
    for (int c = 0; c < 4; c++) {
      int gn = tn + wn + c * 16 + l16;
      float bv = bias[gn];
#pragma unroll
      for (int g = 0; g < 4; g++) {
        int gm = tm + wm + r * 16 + quad * 4 + g;
        outf[(size_t)gm * SD + gn] = acc[r][c][g] + bv;
      }
    }
  }
}

// ---------------- flash attention v12: v9 + s_setprio on MFMA clusters ---
// v11 post-mortem: hand-pipelining was NEUTRAL -- v9's loop has no barriers
// and no LDS ops, so the compiler scheduler was already hoisting PV and
// prefetches across the QK->exp2 boundary; the manual version just added
// 32 VGPRs of live state.  v12 = verified v9 structure + T5 s_setprio(1)
// around MFMA clusters: with 2 waves/SIMD at independent phases (no intra-
// loop barriers), raising priority during a wave's MFMA burst keeps the
// matrix pipe fed while the sibling wave runs its VALU burst (catalog
// m191: +4-7% on attn; null only on barrier-lockstep GEMM, m190).
// Zero register cost (SALU).
__global__ __launch_bounds__(128, 2) void attn(
    const u16* __restrict__ qb, const u16* __restrict__ kb,
    const u16* __restrict__ vfrag, u16* __restrict__ ctxb) {
  int lane = threadIdx.x & 63;
  int wave = threadIdx.x >> 6;          // 0 or 1: kv-half owner
  int l16 = lane & 15, quad = lane >> 4;

  // XCD swizzle: 4 heads per XCD residue (2 MB K+V working set per L2)
  int raw = blockIdx.x;                // 0..1023
  int xcd = raw & 7, slot = raw >> 3;  // slot 0..127
  int bh = xcd + 8 * (slot >> 5);
  int qt = slot & 31;
  int b = bh >> 4, h = bh & 15;
  int base = bh * (SS * SHD);
  int q0 = qt * 64;

  const u16* kp = kb + base + lane * 8;                 // + (kt*8+ct*2+hh)*512
  const u16* vp = vfrag + base + (l16 * 4 + quad) * 8;  // + kt*4096 + (c*2+c2)*512

  // Q fragments (B operand of S^T), fragment-major: kt=qt, ct=t
  short8 qf[4][2];
#pragma unroll
  for (int t = 0; t < 4; t++)
#pragma unroll
    for (int hh = 0; hh < 2; hh++)
      qf[t][hh] = *(const short8*)&qb[base + (qt * 8 + t * 2 + hh) * 512 + lane * 8];

  floatx4 zf = {0.f, 0.f, 0.f, 0.f};
  floatx4 acc[4][4], accl[4];
#pragma unroll
  for (int t = 0; t < 4; t++) {
    accl[t] = zf;
#pragma unroll
    for (int c = 0; c < 4; c++) acc[t][c] = zf;
  }
  const short8 ones8 = {0x3F80, 0x3F80, 0x3F80, 0x3F80,
                        0x3F80, 0x3F80, 0x3F80, 0x3F80};  // bf16 1.0 x8

  // wave w owns kv-tiles [w*16, w*16+16)
  int ktbase = wave * 16;
  short8 kf[4][2], vf[4][2];
  {
    const u16* p = kp + ktbase * 4096;
#pragma unroll
    for (int ct = 0; ct < 4; ct++)
#pragma unroll
      for (int hh = 0; hh < 2; hh++)
        kf[ct][hh] = *(const short8*)&p[(ct * 2 + hh) * 512];
    const u16* pv = vp + ktbase * 4096;
#pragma unroll
    for (int c = 0; c < 4; c++)
#pragma unroll
      for (int c2 = 0; c2 < 2; c2++)
        vf[c][c2] = *(const short8*)&pv[(c * 2 + c2) * 512];
  }

#pragma unroll 1
  for (int i = 0; i < 16; i++) {
    int nt = ktbase + ((i + 1) & 15);   // next tile; wrap-safe dummy on last
    const u16* kpn = kp + nt * 4096;
    const u16* vpn = vp + nt * 4096;
#pragma unroll
    for (int c2 = 0; c2 < 2; c2++) {
      const int ct0 = 2 * c2, ct1 = 2 * c2 + 1;
      // QK^T for the ct pair: scores se (ct even), so (ct odd)
      floatx4 se[4], so[4];
      __builtin_amdgcn_s_setprio(1);
#pragma unroll
      for (int t = 0; t < 4; t++) {
        floatx4 zz = zf;
        zz = __builtin_amdgcn_mfma_f32_16x16x32_bf16(kf[ct0][0], qf[t][0], zz, 0, 0, 0);
        zz = __builtin_amdgcn_mfma_f32_16x16x32_bf16(kf[ct0][1], qf[t][1], zz, 0, 0, 0);
        se[t] = zz;
        floatx4 ww = zf;
        ww = __builtin_amdgcn_mfma_f32_16x16x32_bf16(kf[ct1][0], qf[t][0], ww, 0, 0, 0);
        ww = __builtin_amdgcn_mfma_f32_16x16x32_bf16(kf[ct1][1], qf[t][1], ww, 0, 0, 0);
        so[t] = ww;
      }
      __builtin_amdgcn_s_setprio(0);
      // kf[ct0], kf[ct1] dead now: prefetch next tile's pair (WAR keeps order)
      kf[ct0][0] = *(const short8*)&kpn[(ct0 * 2 + 0) * 512];
      kf[ct0][1] = *(const short8*)&kpn[(ct0 * 2 + 1) * 512];
      kf[ct1][0] = *(const short8*)&kpn[(ct1 * 2 + 0) * 512];
      kf[ct1][1] = *(const short8*)&kpn[(ct1 * 2 + 1) * 512];
      // exp2 -> pack pa[t] = [P(ct even) | P(ct odd)] keys quad*4+j each
#pragma unroll
      for (int t = 0; t < 4; t++) {
        u32 e0 = __builtin_bit_cast(u32, __builtin_amdgcn_exp2f(se[t][0]));
        u32 e1 = __builtin_bit_cast(u32, __builtin_amdgcn_exp2f(se[t][1]));
        u32 e2 = __builtin_bit_cast(u32, __builtin_amdgcn_exp2f(se[t][2]));
        u32 e3 = __builtin_bit_cast(u32, __builtin_amdgcn_exp2f(se[t][3]));
        u32 o0 = __builtin_bit_cast(u32, __builtin_amdgcn_exp2f(so[t][0]));
        u32 o1 = __builtin_bit_cast(u32, __builtin_amdgcn_exp2f(so[t][1]));
        u32 o2 = __builtin_bit_cast(u32, __builtin_amdgcn_exp2f(so[t][2]));
        u32 o3 = __builtin_bit_cast(u32, __builtin_amdgcn_exp2f(so[t][3]));
        union { u32 u[4]; short8 s; } pa;
        pa.u[0] = __builtin_amdgcn_perm(e1, e0, 0x07060302);  // bf16(e0),bf16(e1)
        pa.u[1] = __builtin_amdgcn_perm(e3, e2, 0x07060302);
        pa.u[2] = __builtin_amdgcn_perm(o1, o0, 0x07060302);
        pa.u[3] = __builtin_amdgcn_perm(o3, o2, 0x07060302);
        __builtin_amdgcn_s_setprio(1);
#pragma unroll
        for (int c = 0; c < 4; c++)
          acc[t][c] = __builtin_amdgcn_mfma_f32_16x16x32_bf16(pa.s, vf[c][c2], acc[t][c], 0, 0, 0);
        accl[t] = __builtin_amdgcn_mfma_f32_16x16x32_bf16(pa.s, ones8, accl[t], 0, 0, 0);
        __builtin_amdgcn_s_setprio(0);
      }
      // vf[*][c2] dead now: prefetch next tile's c2 half
#pragma unroll
      for (int c = 0; c < 4; c++)
        vf[c][c2] = *(const short8*)&vpn[(c * 2 + c2) * 512];
    }
  }

  // Cross-wave combine: wave w publishes the OTHER wave's t-half, then each
  // wave sums partials for its own t-half and stores those 32 q-rows.
  // All acc/accl indexing stays compile-time; t-half selection is a uniform
  // branch (runtime-indexed ext_vector arrays would spill to scratch).
  __shared__ floatx4 red[2][64][11];  // [dest wave][lane][(t&1)*5 + c; 4=accl]
  int ow = 1 - wave;
#pragma unroll
  for (int t = 0; t < 4; t++) {
    if ((t >> 1) == ow) {
#pragma unroll
      for (int c = 0; c < 4; c++) red[ow][lane][(t & 1) * 5 + c] = acc[t][c];
      red[ow][lane][(t & 1) * 5 + 4] = accl[t];
    }
  }
  __syncthreads();
#pragma unroll
  for (int t = 0; t < 4; t++) {
    if ((t >> 1) == wave) {
#pragma unroll
      for (int c = 0; c < 4; c++) acc[t][c] += red[wave][lane][(t & 1) * 5 + c];
      accl[t] += red[wave][lane][(t & 1) * 5 + 4];
    }
  }

  // epilogue: l per-row in accl (no shuffles); each wave stores its t-half
#pragma unroll
  for (int t = 0; t < 4; t++) {
    if ((t >> 1) == wave) {
#pragma unroll
      for (int g = 0; g < 4; g++) {
        float invg = 1.0f / accl[t][g];
        int qrow = q0 + t * 16 + quad * 4 + g;
#pragma unroll
        for (int c = 0; c < 4; c++) {
          int hd = c * 16 + l16;
          ctxb[(size_t)((b * SS + qrow) * SD + h * SHD + hd)] = f2bf(acc[t][c][g] * invg);
        }
      }
    }
  }
}

// ---------------- launch ----------------
extern "C" void kernel_launch(void* const* d_in, const int* in_sizes, int n_in,
                              void* d_out, int out_size, void* d_ws, size_t ws_size,
                              hipStream_t stream) {
  const float* Q  = (const float*)d_in[0];
  const float* Kp = (const float*)d_in[1];
  const float* Vp = (const float*)d_in[2];
  const float* Wq = (const float*)d_in[3];
  const float* bq = (const float*)d_in[4];
  const float* Wk = (const float*)d_in[5];
  const float* bk = (const float*)d_in[6];
  const float* Wv = (const float*)d_in[7];
  const float* bv = (const float*)d_in[8];
  const float* Wo = (const float*)d_in[9];
  const float* bo = (const float*)d_in[10];

  u16* xb   = (u16*)d_ws;                        // 3 * 4,194,304  bf16 Q,K,V
  u16* wb   = xb + (size_t)3 * 4194304;          // 4 * 1,048,576  bf16 weights
  u16* qkvb = wb + (size_t)4 * 1048576;          // q,k frag-major; V frag-major
  u16* ctxb = qkvb + (size_t)3 * 4194304;        // ctx [B,S,D]
  float* out = (float*)d_out;

  cast_all<<<dim3(16384), dim3(256), 0, stream>>>(Q, Kp, Vp, Wq, Wk, Wv, Wo, xb);

  const float qscale = 0.125f * LOG2E;
  gemm_bt<<<dim3(8, 32, 3), dim3(256), 0, stream>>>(
      xb, wb, bq, bk, bv, qkvb, (float*)nullptr, 0, qscale);

  attn<<<dim3(1024), dim3(128), 0, stream>>>(
      qkvb, qkvb + (size_t)4194304, qkvb + (size_t)2 * 4194304, ctxb);

  gemm_o<<<dim3(8, 64), dim3(256), 0, stream>>>(
      ctxb, wb + (size_t)3 * 1048576, bo, out);
}